// Round 6
// baseline (455.197 us; speedup 1.0000x reference)
//
#include <hip/hip_runtime.h>

// CKKS-style polynomial softmax over rows of 2048 fp32. x: [16, 2048, 2048].
// Round-6: completes the 2x2 cache-hint matrix on the clean 2-row ping-pong.
//   R4 cached/cached = 439 | R5 nt/nt = 427 | R6 = CACHED loads + NT stores.
// Mechanism: R2 measured FETCH_SIZE = 134 MB with cached loads -> L3 serves
// half the 268 MB input across bench iterations. With NT stores the 268 MB
// output stream never allocates in L2/L3, so the input is the ONLY tenant
// of the 256 MB L3 (no thrash, unlike R4's cached stores) -> read traffic
// halves while writes stream at R5's rate. In-kernel HBM ~537 -> ~400 MB.
// Structure unchanged from R5 (single-variable A/B):
//   loadA(r0); loadB(r1); procA; procB;  -- procA waits vmcnt(8) with B's
//   loads in flight; procB's loads are older than A's stores (no coupling);
//   no refill (no WAR drain); 2x machine oversubscription; contiguous pair.
// No LDS, no __syncthreads; row-sum = in-wave shfl_xor butterfly.

typedef float v4f __attribute__((ext_vector_type(4)));

#define ROWLEN          2048
#define TPB             256
#define WPB             (TPB / 64)   // 4 waves per block
#define ROWS_PER_WAVE   2
// grid = 32768 / (4*2) = 4096 blocks = 16384 waves = 2x machine capacity.

__global__ __launch_bounds__(TPB, 4) void ckks_softmax_kernel(
    const float* __restrict__ x,
    const float* __restrict__ exp_c,   // 9 coeffs, power basis
    const float* __restrict__ inv_c,   // 5 coeffs
    const int*   __restrict__ iters_p, // single int (==3)
    float* __restrict__ out)
{
    const int lane = threadIdx.x & 63;
    const int wid  = blockIdx.x * WPB + (threadIdx.x >> 6);

    // Uniform coefficient loads -> SGPRs.
    const float c0 = exp_c[0], c1 = exp_c[1], c2 = exp_c[2], c3 = exp_c[3],
                c4 = exp_c[4], c5 = exp_c[5], c6 = exp_c[6], c7 = exp_c[7],
                c8 = exp_c[8];
    const float i0 = inv_c[0], i1 = inv_c[1], i2 = inv_c[2], i3 = inv_c[3],
                i4 = inv_c[4];
    const int iters = *iters_p;

    auto horner8 = [&](float t) -> float {
        float acc = c8;
        acc = fmaf(acc, t, c7);
        acc = fmaf(acc, t, c6);
        acc = fmaf(acc, t, c5);
        acc = fmaf(acc, t, c4);
        acc = fmaf(acc, t, c3);
        acc = fmaf(acc, t, c2);
        acc = fmaf(acc, t, c1);
        acc = fmaf(acc, t, c0);
        return acc;
    };

    auto loadrow = [&](v4f (&buf)[8], size_t row) {
        // PLAIN cached loads: input is read-only and ~L3-sized; with NT
        // stores keeping the output out of the cache hierarchy, the input
        // stays L3-resident across bench iterations (measured: FETCH=134MB).
        const v4f* __restrict__ src = (const v4f*)(x + row * ROWLEN);
        #pragma unroll
        for (int k = 0; k < 8; ++k)
            buf[k] = src[lane + 64 * k];
    };

    auto procrow = [&](v4f (&buf)[8], size_t row) {
        // e = poly_exp(x); keep e resident; shallow partial-sum tree.
        v4f acc4 = {0.0f, 0.0f, 0.0f, 0.0f};
        #pragma unroll
        for (int k = 0; k < 8; ++k) {
            v4f e;
            e.x = horner8(buf[k].x);
            e.y = horner8(buf[k].y);
            e.z = horner8(buf[k].z);
            e.w = horner8(buf[k].w);
            buf[k] = e;
            acc4 += e;
        }
        float s = (acc4.x + acc4.y) + (acc4.z + acc4.w);

        // In-wave butterfly: every lane ends with the full row sum.
        #pragma unroll
        for (int off = 32; off > 0; off >>= 1)
            s += __shfl_xor(s, off, 64);

        // Initial reciprocal guess (degree-4 Horner), redundant per lane.
        float y = i4;
        y = fmaf(y, s, i3);
        y = fmaf(y, s, i2);
        y = fmaf(y, s, i1);
        y = fmaf(y, s, i0);

        // Newton-Raphson: y <- y * (2 - s*y).
        for (int i = 0; i < iters; ++i)
            y = y * (2.0f - s * y);

        // NT stores: pure write stream to HBM, zero L2/L3 allocation -- the
        // write stream neither thrashes the L3-resident input nor leaves
        // dirty lines for the harness poison fill to evict.
        v4f* __restrict__ dst = (v4f*)(out + row * ROWLEN);
        #pragma unroll
        for (int k = 0; k < 8; ++k)
            __builtin_nontemporal_store(buf[k] * y, &dst[lane + 64 * k]);
    };

    v4f A[8], B[8];
    const size_t r0 = (size_t)wid * ROWS_PER_WAVE;   // contiguous pair
    const size_t r1 = r0 + 1;

    loadrow(A, r0);   // 8 loads in flight
    loadrow(B, r1);   // 16 in flight, 16 KB sequential per wave
    procrow(A, r0);   // waits vmcnt(8); B rides under A's compute
    procrow(B, r1);   // waits only B's loads (older than A's stores)
}

extern "C" void kernel_launch(void* const* d_in, const int* in_sizes, int n_in,
                              void* d_out, int out_size, void* d_ws, size_t ws_size,
                              hipStream_t stream) {
    const float* x     = (const float*)d_in[0];
    const float* exp_c = (const float*)d_in[1];
    const float* inv_c = (const float*)d_in[2];
    const int*   iters = (const int*)d_in[3];
    float* out = (float*)d_out;

    const int n_rows   = out_size / ROWLEN;                    // 32768
    const int n_blocks = n_rows / (WPB * ROWS_PER_WAVE);       // 4096
    ckks_softmax_kernel<<<n_blocks, TPB, 0, stream>>>(x, exp_c, inv_c, iters, out);
}

// Round 7
// 430.530 us; speedup vs baseline: 1.0573x; 1.0573x over previous
//
#include <hip/hip_runtime.h>

// CKKS-style polynomial softmax over rows of 2048 fp32. x: [16, 2048, 2048].
// Round-7: the missing cell of the cache-hint 2x2 -> NT loads + PLAIN stores.
//   bench:  plain/plain 431,439 | nt/nt 424,427 | plain/nt 449,455 (worst)
//   additive model predicts nt/plain ~411 (best).
// Mechanism: NT loads bypass L2/L3 allocation entirely (no churn, no probe
// serialization; R6 proved cached-load byte savings buy zero time). PLAIN
// stores retire into L2 and write back asynchronously -- the same store path
// the 6.5 TB/s rocclr fill uses; R5/R6's nt stores forced the full 268 MB
// write drain inside the kernel window.
// Structure unchanged from R5/R6 (single-variable A/B vs R5):
//   loadA(r0); loadB(r1); procA; procB;  -- procA waits vmcnt(8) with B's
//   loads in flight; procB's loads are older than A's stores (no coupling);
//   no refill (no WAR drain); 2x machine oversubscription; contiguous pair.
// No LDS, no __syncthreads; row-sum = in-wave shfl_xor butterfly.

typedef float v4f __attribute__((ext_vector_type(4)));

#define ROWLEN          2048
#define TPB             256
#define WPB             (TPB / 64)   // 4 waves per block
#define ROWS_PER_WAVE   2
// grid = 32768 / (4*2) = 4096 blocks = 16384 waves = 2x machine capacity.

__global__ __launch_bounds__(TPB, 4) void ckks_softmax_kernel(
    const float* __restrict__ x,
    const float* __restrict__ exp_c,   // 9 coeffs, power basis
    const float* __restrict__ inv_c,   // 5 coeffs
    const int*   __restrict__ iters_p, // single int (==3)
    float* __restrict__ out)
{
    const int lane = threadIdx.x & 63;
    const int wid  = blockIdx.x * WPB + (threadIdx.x >> 6);

    // Uniform coefficient loads -> SGPRs.
    const float c0 = exp_c[0], c1 = exp_c[1], c2 = exp_c[2], c3 = exp_c[3],
                c4 = exp_c[4], c5 = exp_c[5], c6 = exp_c[6], c7 = exp_c[7],
                c8 = exp_c[8];
    const float i0 = inv_c[0], i1 = inv_c[1], i2 = inv_c[2], i3 = inv_c[3],
                i4 = inv_c[4];
    const int iters = *iters_p;

    auto horner8 = [&](float t) -> float {
        float acc = c8;
        acc = fmaf(acc, t, c7);
        acc = fmaf(acc, t, c6);
        acc = fmaf(acc, t, c5);
        acc = fmaf(acc, t, c4);
        acc = fmaf(acc, t, c3);
        acc = fmaf(acc, t, c2);
        acc = fmaf(acc, t, c1);
        acc = fmaf(acc, t, c0);
        return acc;
    };

    auto loadrow = [&](v4f (&buf)[8], size_t row) {
        // NT loads: pure HBM read stream, zero L2/L3 allocation churn.
        const v4f* __restrict__ src = (const v4f*)(x + row * ROWLEN);
        #pragma unroll
        for (int k = 0; k < 8; ++k)
            buf[k] = __builtin_nontemporal_load(&src[lane + 64 * k]);
    };

    auto procrow = [&](v4f (&buf)[8], size_t row) {
        // e = poly_exp(x); keep e resident; shallow partial-sum tree.
        v4f acc4 = {0.0f, 0.0f, 0.0f, 0.0f};
        #pragma unroll
        for (int k = 0; k < 8; ++k) {
            v4f e;
            e.x = horner8(buf[k].x);
            e.y = horner8(buf[k].y);
            e.z = horner8(buf[k].z);
            e.w = horner8(buf[k].w);
            buf[k] = e;
            acc4 += e;
        }
        float s = (acc4.x + acc4.y) + (acc4.z + acc4.w);

        // In-wave butterfly: every lane ends with the full row sum.
        #pragma unroll
        for (int off = 32; off > 0; off >>= 1)
            s += __shfl_xor(s, off, 64);

        // Initial reciprocal guess (degree-4 Horner), redundant per lane.
        float y = i4;
        y = fmaf(y, s, i3);
        y = fmaf(y, s, i2);
        y = fmaf(y, s, i1);
        y = fmaf(y, s, i0);

        // Newton-Raphson: y <- y * (2 - s*y).
        for (int i = 0; i < iters; ++i)
            y = y * (2.0f - s * y);

        // PLAIN stores: retire into L2, asynchronous writeback (fill-style).
        v4f* __restrict__ dst = (v4f*)(out + row * ROWLEN);
        #pragma unroll
        for (int k = 0; k < 8; ++k)
            dst[lane + 64 * k] = buf[k] * y;
    };

    v4f A[8], B[8];
    const size_t r0 = (size_t)wid * ROWS_PER_WAVE;   // contiguous pair
    const size_t r1 = r0 + 1;

    loadrow(A, r0);   // 8 loads in flight
    loadrow(B, r1);   // 16 in flight, 16 KB sequential per wave
    procrow(A, r0);   // waits vmcnt(8); B rides under A's compute
    procrow(B, r1);   // waits only B's loads (older than A's stores)
}

extern "C" void kernel_launch(void* const* d_in, const int* in_sizes, int n_in,
                              void* d_out, int out_size, void* d_ws, size_t ws_size,
                              hipStream_t stream) {
    const float* x     = (const float*)d_in[0];
    const float* exp_c = (const float*)d_in[1];
    const float* inv_c = (const float*)d_in[2];
    const int*   iters = (const int*)d_in[3];
    float* out = (float*)d_out;

    const int n_rows   = out_size / ROWLEN;                    // 32768
    const int n_blocks = n_rows / (WPB * ROWS_PER_WAVE);       // 4096
    ckks_softmax_kernel<<<n_blocks, TPB, 0, stream>>>(x, exp_c, inv_c, iters, out);
}